// Round 2
// baseline (314.507 us; speedup 1.0000x reference)
//
#include <hip/hip_runtime.h>
#include <math.h>

#define NROWS 8192
#define BHALF 4096
#define DDIM  128
#define NSPLIT 4          // column splits (grid.y)
#define COLS_PER_SPLIT (NROWS / NSPLIT)   // 2048
#define TM 64             // rows per block
#define TN 64             // cols per inner tile

// ---------------------------------------------------------------------------
// Kernel 1: L2-normalize rows of [zis; zjs] and write rep^T [DDIM][NROWS].
// One wave per row; lane l owns elements 2l, 2l+1.
// ---------------------------------------------------------------------------
__global__ __launch_bounds__(256) void nt_normalize(const float* __restrict__ zis,
                                                    const float* __restrict__ zjs,
                                                    float* __restrict__ repT) {
    int row  = blockIdx.x * 4 + (threadIdx.x >> 6);
    int lane = threadIdx.x & 63;
    const float* src = (row < BHALF) ? (zis + (size_t)row * DDIM)
                                     : (zjs + (size_t)(row - BHALF) * DDIM);
    float2 v = ((const float2*)src)[lane];
    float ss = v.x * v.x + v.y * v.y;
    #pragma unroll
    for (int off = 1; off < 64; off <<= 1) ss += __shfl_xor(ss, off);
    float inv = 1.0f / fmaxf(sqrtf(ss), 1e-12f);
    repT[(size_t)(2 * lane)     * NROWS + row] = v.x * inv;
    repT[(size_t)(2 * lane + 1) * NROWS + row] = v.y * inv;
}

// ---------------------------------------------------------------------------
// Kernel 2: fused sim-tile GEMM + online logsumexp (diagonal excluded).
// Block: 64 rows x 2048 cols. 256 threads as 16x16, each owns a 4x4 tile.
// LDS: A^T[k][row] and B^T[k][col], both 128x64 f32 (32 KB each).
// Writes per-(split,row) partial (m, s) to ws.
// ---------------------------------------------------------------------------
__global__ __launch_bounds__(256) void nt_simlse(const float* __restrict__ repT,
                                                 float* __restrict__ partial) {
    __shared__ float At[DDIM][TM];
    __shared__ float Bt[DDIM][TN];

    const int i0 = blockIdx.x * TM;
    const int j0base = blockIdx.y * COLS_PER_SPLIT;
    const int t = threadIdx.x;
    const int tr = t >> 4;      // 0..15 row group
    const int tc = t & 15;      // 0..15 col group

    // Load A tile: At[k][c] = repT[k][i0+c]; 2048 float4 slots over 256 thr.
    #pragma unroll
    for (int s = 0; s < 8; ++s) {
        int slot = t + s * 256;
        int k  = slot >> 4;
        int c4 = (slot & 15) * 4;
        *(float4*)&At[k][c4] = *(const float4*)&repT[(size_t)k * NROWS + i0 + c4];
    }

    float m[4], ssum[4];
    #pragma unroll
    for (int r = 0; r < 4; ++r) { m[r] = -INFINITY; ssum[r] = 0.0f; }

    for (int jt = 0; jt < COLS_PER_SPLIT / TN; ++jt) {
        const int j0 = j0base + jt * TN;
        __syncthreads();
        #pragma unroll
        for (int s = 0; s < 8; ++s) {
            int slot = t + s * 256;
            int k  = slot >> 4;
            int c4 = (slot & 15) * 4;
            *(float4*)&Bt[k][c4] = *(const float4*)&repT[(size_t)k * NROWS + j0 + c4];
        }
        __syncthreads();

        float acc[4][4];
        #pragma unroll
        for (int r = 0; r < 4; ++r)
            #pragma unroll
            for (int c = 0; c < 4; ++c) acc[r][c] = 0.0f;

        #pragma unroll 8
        for (int k = 0; k < DDIM; ++k) {
            float4 a = *(const float4*)&At[k][tr * 4];
            float4 b = *(const float4*)&Bt[k][tc * 4];
            float av[4] = {a.x, a.y, a.z, a.w};
            float bv[4] = {b.x, b.y, b.z, b.w};
            #pragma unroll
            for (int r = 0; r < 4; ++r)
                #pragma unroll
                for (int c = 0; c < 4; ++c)
                    acc[r][c] = fmaf(av[r], bv[c], acc[r][c]);
        }

        // Online LSE update per owned row.
        #pragma unroll
        for (int r = 0; r < 4; ++r) {
            const int gi = i0 + tr * 4 + r;
            float v[4];
            #pragma unroll
            for (int c = 0; c < 4; ++c) {
                v[c] = 2.0f * acc[r][c];              // / TEMPERATURE (0.5)
                if (gi == j0 + tc * 4 + c) v[c] = -INFINITY;  // mask diagonal
            }
            float mx = fmaxf(fmaxf(v[0], v[1]), fmaxf(v[2], v[3]));
            float nm = fmaxf(m[r], mx);               // finite after 1st tile
            float e  = ssum[r] * __expf(m[r] - nm);
            #pragma unroll
            for (int c = 0; c < 4; ++c) e += __expf(v[c] - nm);
            m[r] = nm; ssum[r] = e;
        }
    }

    // Merge across the 16 threads (consecutive lanes, same wave) sharing rows.
    #pragma unroll
    for (int r = 0; r < 4; ++r) {
        float mr = m[r], sr = ssum[r];
        #pragma unroll
        for (int off = 1; off < 16; off <<= 1) {
            float om = __shfl_xor(mr, off);
            float os = __shfl_xor(sr, off);
            float nm = fmaxf(mr, om);
            sr = sr * __expf(mr - nm) + os * __expf(om - nm);
            mr = nm;
        }
        if (tc == 0) {
            const int gi = i0 + tr * 4 + r;
            partial[((size_t)blockIdx.y * NROWS + gi) * 2 + 0] = mr;
            partial[((size_t)blockIdx.y * NROWS + gi) * 2 + 1] = sr;
        }
    }
}

// ---------------------------------------------------------------------------
// Kernel 3: per-row merge of split partials + pos dot + final loss reduce.
// One wave per 64 rows; lane owns one row.
// ---------------------------------------------------------------------------
__global__ __launch_bounds__(64) void nt_merge(const float* __restrict__ repT,
                                               const float* __restrict__ partial,
                                               float* __restrict__ out) {
    const int i = blockIdx.x * 64 + threadIdx.x;
    const int j = i ^ BHALF;     // positive pair index
    float acc = 0.0f;
    #pragma unroll 16
    for (int d = 0; d < DDIM; ++d)
        acc = fmaf(repT[(size_t)d * NROWS + i], repT[(size_t)d * NROWS + j], acc);

    float mr = -INFINITY, sr = 0.0f;
    #pragma unroll
    for (int p = 0; p < NSPLIT; ++p) {
        float pm = partial[((size_t)p * NROWS + i) * 2 + 0];
        float ps = partial[((size_t)p * NROWS + i) * 2 + 1];
        float nm = fmaxf(mr, pm);
        sr = sr * __expf(mr - nm) + ps * __expf(pm - nm);
        mr = nm;
    }
    float val = mr + logf(sr) - 2.0f * acc;   // lse_i - pos_i

    #pragma unroll
    for (int off = 1; off < 64; off <<= 1) val += __shfl_xor(val, off);
    if (threadIdx.x == 0) atomicAdd(out, val * (1.0f / (float)NROWS));
}

// ---------------------------------------------------------------------------
extern "C" void kernel_launch(void* const* d_in, const int* in_sizes, int n_in,
                              void* d_out, int out_size, void* d_ws, size_t ws_size,
                              hipStream_t stream) {
    const float* zis = (const float*)d_in[0];
    const float* zjs = (const float*)d_in[1];
    float* out = (float*)d_out;

    float* repT    = (float*)d_ws;                                   // 4 MB
    float* partial = (float*)((char*)d_ws +
                     (size_t)DDIM * NROWS * sizeof(float));          // 256 KB

    hipMemsetAsync(out, 0, sizeof(float), stream);
    nt_normalize<<<NROWS / 4, 256, 0, stream>>>(zis, zjs, repT);
    nt_simlse<<<dim3(NROWS / TM, NSPLIT), 256, 0, stream>>>(repT, partial);
    nt_merge<<<NROWS / 64, 64, 0, stream>>>(repT, partial, out);
}

// Round 5
// 115.318 us; speedup vs baseline: 2.7273x; 2.7273x over previous
//
#include <hip/hip_runtime.h>
#include <math.h>
#include <stdint.h>

#define NROWS 8192
#define BHALF 4096
#define DDIM  128
#define NSPLIT 8
#define COLS_PER_BLOCK (NROWS / NSPLIT)   // 1024
#define CHUNK 64                          // cols staged per LDS chunk
#define NCHUNK (COLS_PER_BLOCK / CHUNK)   // 16

typedef __bf16 bf16;
typedef __bf16 bf16x2 __attribute__((ext_vector_type(2)));
typedef __bf16 bf16x8 __attribute__((ext_vector_type(8)));
typedef float  f32x4  __attribute__((ext_vector_type(4)));

#define MFMA(acc, va, vb) \
    acc = __builtin_amdgcn_mfma_f32_16x16x32_bf16(va, vb, acc, 0, 0, 0)

// ---------------------------------------------------------------------------
// Kernel 1: L2-normalize rows of [zis; zjs], split fp32 -> bf16 hi + lo.
// rhi/rlo are [NROWS][DDIM] row-major. One wave per row.
// ---------------------------------------------------------------------------
__global__ __launch_bounds__(256) void nt_prep(const float* __restrict__ zis,
                                               const float* __restrict__ zjs,
                                               bf16* __restrict__ rhi,
                                               bf16* __restrict__ rlo) {
    int row  = blockIdx.x * 4 + (threadIdx.x >> 6);
    int lane = threadIdx.x & 63;
    const float* src = (row < BHALF) ? (zis + (size_t)row * DDIM)
                                     : (zjs + (size_t)(row - BHALF) * DDIM);
    float2 v = ((const float2*)src)[lane];
    float ss = v.x * v.x + v.y * v.y;
    #pragma unroll
    for (int off = 1; off < 64; off <<= 1) ss += __shfl_xor(ss, off);
    float inv = 1.0f / fmaxf(sqrtf(ss), 1e-12f);
    float x0 = v.x * inv, x1 = v.y * inv;
    bf16 h0 = (bf16)x0, h1 = (bf16)x1;
    bf16 l0 = (bf16)(x0 - (float)h0), l1 = (bf16)(x1 - (float)h1);
    bf16x2 hv, lv;
    hv[0] = h0; hv[1] = h1; lv[0] = l0; lv[1] = l1;
    *(bf16x2*)(rhi + (size_t)row * DDIM + 2 * lane) = hv;
    *(bf16x2*)(rlo + (size_t)row * DDIM + 2 * lane) = lv;
}

// ---------------------------------------------------------------------------
// Kernel 2: sim = rep.rep^T via split-bf16 MFMA, fused exp-sum (m fixed at 2).
// Swapped operands: T[j][i] tile => each lane's C/D "col" (lane&15) is a sim
// ROW i; j spread over (lane>>4, reg). Per wave: 32 rows (2 groups of 16) in
// register fragments; cols streamed via LDS chunks of 64 (double-buffered,
// global_load_lds w/ inverse-swizzled source + XOR-swizzled ds_read_b128).
// Writes partial[split][row] = sum_j!=i exp(2*sim_ij - 2) over its col range.
// ---------------------------------------------------------------------------
__global__ __launch_bounds__(256) void nt_sim(const bf16* __restrict__ rhi,
                                              const bf16* __restrict__ rlo,
                                              float* __restrict__ partial) {
    // LDS: 2 buffers x (hi 16KB + lo 16KB) = 64 KB
    __shared__ __align__(16) char smem[65536];

    const int tid  = threadIdx.x;
    const int lane = tid & 63;
    const int w    = tid >> 6;      // wave 0..3
    const int q    = lane >> 4;     // 0..3 (k-chunk group for fragments)
    const int r15  = lane & 15;
    const int x7   = lane & 7;

    const int i0 = blockIdx.x * 128;              // block row base
    const int j0 = blockIdx.y * COLS_PER_BLOCK;   // block col base

    // ---- row fragments (B operand), resident in VGPRs all kernel ----
    // frag kk: lane holds rep[row = base + (lane&15)][k = kk*32 + q*8 .. +8)
    bf16x8 rh[2][4], rl[2][4];
    #pragma unroll
    for (int g = 0; g < 2; ++g) {
        int row = i0 + w * 32 + g * 16 + r15;
        #pragma unroll
        for (int kk = 0; kk < 4; ++kk) {
            rh[g][kk] = *(const bf16x8*)(rhi + (size_t)row * DDIM + kk * 32 + q * 8);
            rl[g][kk] = *(const bf16x8*)(rlo + (size_t)row * DDIM + kk * 32 + q * 8);
        }
    }

    // per-lane swizzled 16B-slot byte offsets for col-frag ds_reads:
    // slot(kk) = kk*4 + q, stored at slot ^ (col&7); col&7 == lane&7 here.
    int po[4];
    #pragma unroll
    for (int kk = 0; kk < 4; ++kk) po[kk] = ((((kk << 2) | q)) ^ x7) << 4;

    float s[2][4];
    #pragma unroll
    for (int g = 0; g < 2; ++g)
        #pragma unroll
        for (int r = 0; r < 4; ++r) s[g][r] = 0.0f;

    const float C2 = 2.8853900817779268f;  // 2*log2(e): exp(v-2)=exp2(C2*(a-1))

    // ---- staging: waves 0,1 stage hi (col groups 0..15), waves 2,3 stage lo.
    // LDS target layout per region: col*256B row, 16B slot s at s^(col&7).
    // global_load_lds writes linearly (lane*16), so the SOURCE slot is
    // inverse-permuted: lane reads slot (lane&15)^(col&7) of its col.
    const bf16* srcb = (w < 2) ? rhi : rlo;
    const int   roff = (w < 2) ? 0 : 16384;

    for (int c = 0; c < NCHUNK + 1; ++c) {
        // stage chunk c into buffer c&1 (skip once past the end)
        if (c < NCHUNK) {
            char* dstb = smem + (c & 1) * 32768 + roff;
            const int colbase = j0 + c * CHUNK;
            #pragma unroll
            for (int s_ = 0; s_ < 8; ++s_) {
                int cg   = (w & 1) * 8 + s_;        // col group 0..15 (4 cols)
                int colw = cg * 4 + q;              // col within chunk
                int grow = colbase + colw;          // global rep row (sim col)
                int slot = r15 ^ (colw & 7);
                const bf16* src = srcb + (size_t)grow * DDIM + slot * 8;
                __builtin_amdgcn_global_load_lds(
                    (const __attribute__((address_space(1))) void*)src,
                    (__attribute__((address_space(3))) void*)(dstb + cg * 1024),
                    16, 0, 0);
            }
        }
        if (c == 0) { __syncthreads(); continue; }  // prologue: nothing to compute

        // compute chunk c-1 from buffer (c-1)&1
        const char* bh = smem + ((c - 1) & 1) * 32768;
        const char* bl = bh + 16384;
        const int jchunk = j0 + (c - 1) * CHUNK;
        #pragma unroll
        for (int jt = 0; jt < 4; ++jt) {
            bf16x8 ch[4], cl[4];
            const int cb = jt * 4096 + r15 * 256;
            #pragma unroll
            for (int kk = 0; kk < 4; ++kk) {
                ch[kk] = *(const bf16x8*)(bh + cb + po[kk]);
                cl[kk] = *(const bf16x8*)(bl + cb + po[kk]);
            }
            f32x4 a0 = {0.f, 0.f, 0.f, 0.f}, a1 = {0.f, 0.f, 0.f, 0.f};
            #pragma unroll
            for (int kk = 0; kk < 4; ++kk) {
                MFMA(a0, ch[kk], rh[0][kk]);
                MFMA(a0, ch[kk], rl[0][kk]);
                MFMA(a0, cl[kk], rh[0][kk]);
                MFMA(a1, ch[kk], rh[1][kk]);
                MFMA(a1, ch[kk], rl[1][kk]);
                MFMA(a1, cl[kk], rh[1][kk]);
            }
            // epilogue: s += exp(2*sim - 2), diagonal (i==j) excluded
            const int jb = jchunk + jt * 16 + q * 4;  // j of reg r is jb + r
            #pragma unroll
            for (int g = 0; g < 2; ++g) {
                const int ig = i0 + w * 32 + g * 16 + r15;
                const int dj = ig - jb;
                #pragma unroll
                for (int r = 0; r < 4; ++r) {
                    float a = (g ? a1 : a0)[r];
                    float e = exp2f(fmaf(a, C2, -C2));
                    s[g][r] += (dj == r) ? 0.0f : e;
                }
            }
        }
        __syncthreads();   // staged chunk c landed; everyone done with c-1
    }

    // ---- per-row totals: reduce over reg then over lane>>4 groups ----
    #pragma unroll
    for (int g = 0; g < 2; ++g) {
        float st = (s[g][0] + s[g][1]) + (s[g][2] + s[g][3]);
        st += __shfl_xor(st, 16);
        st += __shfl_xor(st, 32);
        if (q == g)
            partial[(size_t)blockIdx.y * NROWS + i0 + w * 32 + g * 16 + r15] = st;
    }
}

// ---------------------------------------------------------------------------
// Kernel 3: per-row: sum split partials, lse = 2 + log(s); pos = 2*<rep_i,rep_j>
// recomputed in fp32 from hi+lo. rowval[i] = lse_i - pos_i. One wave per row.
// ---------------------------------------------------------------------------
__global__ __launch_bounds__(256) void nt_finish(const bf16* __restrict__ rhi,
                                                 const bf16* __restrict__ rlo,
                                                 const float* __restrict__ partial,
                                                 float* __restrict__ rowval) {
    int i    = blockIdx.x * 4 + (threadIdx.x >> 6);
    int lane = threadIdx.x & 63;
    int j    = i ^ BHALF;
    bf16x2 hi_ = *(const bf16x2*)(rhi + (size_t)i * DDIM + 2 * lane);
    bf16x2 li_ = *(const bf16x2*)(rlo + (size_t)i * DDIM + 2 * lane);
    bf16x2 hj_ = *(const bf16x2*)(rhi + (size_t)j * DDIM + 2 * lane);
    bf16x2 lj_ = *(const bf16x2*)(rlo + (size_t)j * DDIM + 2 * lane);
    float xi0 = (float)hi_[0] + (float)li_[0];
    float xi1 = (float)hi_[1] + (float)li_[1];
    float xj0 = (float)hj_[0] + (float)lj_[0];
    float xj1 = (float)hj_[1] + (float)lj_[1];
    float d = xi0 * xj0 + xi1 * xj1;
    #pragma unroll
    for (int off = 1; off < 64; off <<= 1) d += __shfl_xor(d, off);
    if (lane == 0) {
        float ssum = 0.0f;
        #pragma unroll
        for (int p = 0; p < NSPLIT; ++p) ssum += partial[(size_t)p * NROWS + i];
        rowval[i] = 2.0f + logf(ssum) - 2.0f * d;
    }
}

// ---------------------------------------------------------------------------
// Kernel 4: final mean over 8192 row values (single block; no atomics).
// ---------------------------------------------------------------------------
__global__ __launch_bounds__(256) void nt_reduce(const float* __restrict__ rowval,
                                                 float* __restrict__ out) {
    int t = threadIdx.x;
    const float4* rv4 = (const float4*)rowval;
    float acc = 0.0f;
    #pragma unroll
    for (int k = 0; k < NROWS / 4 / 256; ++k) {
        float4 v = rv4[t + k * 256];
        acc += (v.x + v.y) + (v.z + v.w);
    }
    #pragma unroll
    for (int off = 1; off < 64; off <<= 1) acc += __shfl_xor(acc, off);
    __shared__ float ws4[4];
    if ((t & 63) == 0) ws4[t >> 6] = acc;
    __syncthreads();
    if (t == 0) out[0] = (ws4[0] + ws4[1] + ws4[2] + ws4[3]) * (1.0f / (float)NROWS);
}

// ---------------------------------------------------------------------------
extern "C" void kernel_launch(void* const* d_in, const int* in_sizes, int n_in,
                              void* d_out, int out_size, void* d_ws, size_t ws_size,
                              hipStream_t stream) {
    const float* zis = (const float*)d_in[0];
    const float* zjs = (const float*)d_in[1];
    float* out = (float*)d_out;

    char* ws = (char*)d_ws;
    bf16*  rhi     = (bf16*)ws;                                   // 2 MB
    bf16*  rlo     = (bf16*)(ws + (size_t)NROWS * DDIM * 2);      // 2 MB
    float* partial = (float*)(ws + (size_t)NROWS * DDIM * 4);     // 256 KB
    float* rowval  = (float*)(ws + (size_t)NROWS * DDIM * 4
                                 + (size_t)NSPLIT * NROWS * 4);   // 32 KB

    nt_prep  <<<NROWS / 4, 256, 0, stream>>>(zis, zjs, rhi, rlo);
    nt_sim   <<<dim3(NROWS / 128, NSPLIT), 256, 0, stream>>>(rhi, rlo, partial);
    nt_finish<<<NROWS / 4, 256, 0, stream>>>(rhi, rlo, partial, rowval);
    nt_reduce<<<1, 256, 0, stream>>>(rowval, out);
}

// Round 7
// 113.206 us; speedup vs baseline: 2.7782x; 1.0186x over previous
//
#include <hip/hip_runtime.h>
#include <math.h>

#define NROWS 8192
#define BHALF 4096
#define DDIM  128
#define NSPLIT 16
#define COLS_PER_BLOCK (NROWS / NSPLIT)   // 512
#define CHUNK 32                          // cols staged per LDS chunk
#define NCHUNK (COLS_PER_BLOCK / CHUNK)   // 16

typedef __bf16 bf16;
typedef __bf16 bf16x2 __attribute__((ext_vector_type(2)));
typedef __bf16 bf16x8 __attribute__((ext_vector_type(8)));
typedef float  f32x4  __attribute__((ext_vector_type(4)));

#define MFMA(acc, va, vb) \
    acc = __builtin_amdgcn_mfma_f32_16x16x32_bf16(va, vb, acc, 0, 0, 0)

#define C2F 2.8853900817779268f   // 2*log2(e)
#define SCF 1.6986433053702937f   // sqrt(2*log2(e))

// ---------------------------------------------------------------------------
// Kernel 1: L2-normalize, scale by sqrt(2*log2(e)), split fp32 -> bf16 hi+lo.
// Both MFMA operands come from these arrays, so the product is C2*dot and the
// per-element epilogue needs NO fma: e = exp2(acc) with acc initialized -C2.
// ---------------------------------------------------------------------------
__global__ __launch_bounds__(256) void nt_prep(const float* __restrict__ zis,
                                               const float* __restrict__ zjs,
                                               bf16* __restrict__ rhi,
                                               bf16* __restrict__ rlo) {
    int row  = blockIdx.x * 4 + (threadIdx.x >> 6);
    int lane = threadIdx.x & 63;
    const float* src = (row < BHALF) ? (zis + (size_t)row * DDIM)
                                     : (zjs + (size_t)(row - BHALF) * DDIM);
    float2 v = ((const float2*)src)[lane];
    float ss = v.x * v.x + v.y * v.y;
    #pragma unroll
    for (int off = 1; off < 64; off <<= 1) ss += __shfl_xor(ss, off);
    float invs = SCF / fmaxf(sqrtf(ss), 1e-12f);
    float y0 = v.x * invs, y1 = v.y * invs;
    bf16 h0 = (bf16)y0, h1 = (bf16)y1;
    bf16 l0 = (bf16)(y0 - (float)h0), l1 = (bf16)(y1 - (float)h1);
    bf16x2 hv, lv;
    hv[0] = h0; hv[1] = h1; lv[0] = l0; lv[1] = l1;
    *(bf16x2*)(rhi + (size_t)row * DDIM + 2 * lane) = hv;
    *(bf16x2*)(rlo + (size_t)row * DDIM + 2 * lane) = lv;
}

// ---------------------------------------------------------------------------
// Kernel 2: sim GEMM (3-pass split-bf16 MFMA) + fused exp2 sum.
// No diagonal mask (sim_ii term == 1, subtracted in nt_final). The positive
// logit a = C2*dot-C2 is captured in-kernel by the one block whose col range
// contains i^BHALF. CHUNK=32/NSPLIT=16: LDS 32KB -> 4 blocks/CU.
// ---------------------------------------------------------------------------
__global__ __launch_bounds__(256, 4) void nt_sim(const bf16* __restrict__ rhi,
                                                 const bf16* __restrict__ rlo,
                                                 float* __restrict__ partial,
                                                 float* __restrict__ posA) {
    // LDS: 2 buffers x (hi 8KB + lo 8KB) = 32 KB
    __shared__ __align__(16) char smem[32768];

    const int tid  = threadIdx.x;
    const int lane = tid & 63;
    const int w    = tid >> 6;      // wave 0..3
    const int q    = lane >> 4;     // 0..3
    const int r15  = lane & 15;

    const int i0 = blockIdx.x * 128;              // block row base
    const int j0 = blockIdx.y * COLS_PER_BLOCK;   // block col base
    const bool capture = (blockIdx.y == (unsigned)((i0 ^ BHALF) >> 9));

    // ---- row fragments (B operand), VGPR-resident ----
    bf16x8 rh[2][4], rl[2][4];
    #pragma unroll
    for (int g = 0; g < 2; ++g) {
        int row = i0 + w * 32 + g * 16 + r15;
        #pragma unroll
        for (int kk = 0; kk < 4; ++kk) {
            rh[g][kk] = *(const bf16x8*)(rhi + (size_t)row * DDIM + kk * 32 + q * 8);
            rl[g][kk] = *(const bf16x8*)(rlo + (size_t)row * DDIM + kk * 32 + q * 8);
        }
    }

    float s[2][4];
    #pragma unroll
    for (int g = 0; g < 2; ++g)
        #pragma unroll
        for (int r = 0; r < 4; ++r) s[g][r] = 0.0f;

    for (int c = 0; c <= NCHUNK; ++c) {
        // ---- stage chunk c into buffer c&1 (issued before compute: T14) ----
        if (c < NCHUNK) {
            char* dstb = smem + (c & 1) * 16384;
            const int colbase = j0 + c * CHUNK;
            #pragma unroll
            for (int h2 = 0; h2 < 2; ++h2) {
                const bf16* srcb = h2 ? rlo : rhi;
                char* regbase = dstb + h2 * 8192 + w * 1024;  // wave-uniform
                #pragma unroll
                for (int hf = 0; hf < 2; ++hf) {
                    int col = hf * 16 + w * 4 + q;            // col in chunk
                    const bf16* src = srcb + (size_t)(colbase + col) * DDIM
                                    + ((r15 ^ (col & 7)) << 3);
                    __builtin_amdgcn_global_load_lds(
                        (const __attribute__((address_space(1))) void*)src,
                        (__attribute__((address_space(3))) void*)(regbase + hf * 4096),
                        16, 0, 0);
                }
            }
        }
        if (c == 0) { __syncthreads(); continue; }

        // ---- compute chunk c-1 from buffer (c-1)&1 ----
        const char* bh = smem + ((c - 1) & 1) * 16384;
        const char* bl = bh + 8192;
        const int cc = c - 1;
        #pragma unroll
        for (int jt = 0; jt < 2; ++jt) {
            const int cb = jt * 4096 + r15 * 256;
            f32x4 a0 = {-C2F, -C2F, -C2F, -C2F};
            f32x4 a1 = {-C2F, -C2F, -C2F, -C2F};
            #pragma unroll
            for (int kk = 0; kk < 4; ++kk) {
                int pok = ((((kk << 2) | q)) ^ (r15 & 7)) << 4;
                bf16x8 ch = *(const bf16x8*)(bh + cb + pok);
                bf16x8 cl = *(const bf16x8*)(bl + cb + pok);
                MFMA(a0, ch, rh[0][kk]);
                MFMA(a0, ch, rl[0][kk]);
                MFMA(a0, cl, rh[0][kk]);
                MFMA(a1, ch, rh[1][kk]);
                MFMA(a1, ch, rl[1][kk]);
                MFMA(a1, cl, rh[1][kk]);
            }
            // epilogue: no mask, no fma — just exp2 + accumulate
            #pragma unroll
            for (int r = 0; r < 4; ++r) {
                s[0][r] += exp2f(a0[r]);
                s[1][r] += exp2f(a1[r]);
            }
            // positive-pair logit capture (wave-uniform skip in 15/16 blocks)
            if (capture) {
                const int jbase = j0 + cc * CHUNK + jt * 16;
                #pragma unroll
                for (int g = 0; g < 2; ++g) {
                    const f32x4 a = g ? a1 : a0;
                    int ig  = i0 + w * 32 + g * 16 + r15;
                    int rel = (ig ^ BHALF) - jbase;
                    float v01 = (rel & 1) ? a[1] : a[0];
                    float v23 = (rel & 1) ? a[3] : a[2];
                    float v   = (rel & 2) ? v23 : v01;
                    if (rel >= 0 && rel < 16 && (rel >> 2) == q) posA[ig] = v;
                }
            }
        }
        __syncthreads();
    }

    // ---- per-row totals: reduce regs, then over q groups ----
    #pragma unroll
    for (int g = 0; g < 2; ++g) {
        float st = (s[g][0] + s[g][1]) + (s[g][2] + s[g][3]);
        st += __shfl_xor(st, 16);
        st += __shfl_xor(st, 32);
        if (q == g)
            partial[(size_t)blockIdx.y * NROWS + i0 + w * 32 + g * 16 + r15] = st;
    }
}

// ---------------------------------------------------------------------------
// Kernel 3: merge partials, lse = 2 + log(sum - 1), pos = 2*(a+C2)/C2,
// mean over rows. Single block, deterministic (no atomics, no memset).
// ---------------------------------------------------------------------------
__global__ __launch_bounds__(1024) void nt_final(const float* __restrict__ partial,
                                                 const float* __restrict__ posA,
                                                 float* __restrict__ out) {
    int tid = threadIdx.x;
    float acc = 0.0f;
    #pragma unroll
    for (int rr = 0; rr < NROWS / 1024; ++rr) {
        int i = tid + rr * 1024;
        float ssum = 0.0f;
        #pragma unroll
        for (int p = 0; p < NSPLIT; ++p) ssum += partial[(size_t)p * NROWS + i];
        float a = posA[i];                        // C2*dot_pos - C2
        acc += 2.0f + logf(ssum - 1.0f) - 2.0f * (a + C2F) / C2F;
    }
    #pragma unroll
    for (int off = 1; off < 64; off <<= 1) acc += __shfl_xor(acc, off);
    __shared__ float wsum[16];
    if ((tid & 63) == 0) wsum[tid >> 6] = acc;
    __syncthreads();
    if (tid == 0) {
        float t = 0.0f;
        #pragma unroll
        for (int k = 0; k < 16; ++k) t += wsum[k];
        out[0] = t * (1.0f / (float)NROWS);
    }
}

// ---------------------------------------------------------------------------
extern "C" void kernel_launch(void* const* d_in, const int* in_sizes, int n_in,
                              void* d_out, int out_size, void* d_ws, size_t ws_size,
                              hipStream_t stream) {
    const float* zis = (const float*)d_in[0];
    const float* zjs = (const float*)d_in[1];
    float* out = (float*)d_out;

    char* ws = (char*)d_ws;
    bf16*  rhi     = (bf16*)ws;                                   // 2 MB
    bf16*  rlo     = (bf16*)(ws + (size_t)NROWS * DDIM * 2);      // 2 MB
    float* partial = (float*)(ws + (size_t)NROWS * DDIM * 4);     // 512 KB
    float* posA    = (float*)(ws + (size_t)NROWS * DDIM * 4
                                 + (size_t)NSPLIT * NROWS * 4);   // 32 KB

    nt_prep <<<NROWS / 4, 256, 0, stream>>>(zis, zjs, rhi, rlo);
    nt_sim  <<<dim3(NROWS / 128, NSPLIT), 256, 0, stream>>>(rhi, rlo, partial, posA);
    nt_final<<<1, 1024, 0, stream>>>(partial, posA, out);
}

// Round 8
// 112.761 us; speedup vs baseline: 2.7892x; 1.0040x over previous
//
#include <hip/hip_runtime.h>
#include <math.h>

#define NROWS 8192
#define BHALF 4096
#define DDIM  128
#define NSPLIT 16
#define COLS_PER_BLOCK (NROWS / NSPLIT)   // 512
#define CHUNK 32                          // cols staged per LDS chunk
#define NCHUNK (COLS_PER_BLOCK / CHUNK)   // 16

typedef __bf16 bf16;
typedef __bf16 bf16x2 __attribute__((ext_vector_type(2)));
typedef __bf16 bf16x8 __attribute__((ext_vector_type(8)));
typedef float  f32x4  __attribute__((ext_vector_type(4)));

#define MFMA(acc, va, vb) \
    acc = __builtin_amdgcn_mfma_f32_16x16x32_bf16(va, vb, acc, 0, 0, 0)

#define C2F 2.8853900817779268f   // 2*log2(e)
#define SCF 1.6986433053702937f   // sqrt(2*log2(e))

// ---------------------------------------------------------------------------
// Kernel 1: L2-normalize, scale by sqrt(2*log2(e)), split fp32 -> bf16 hi+lo.
// ---------------------------------------------------------------------------
__global__ __launch_bounds__(256) void nt_prep(const float* __restrict__ zis,
                                               const float* __restrict__ zjs,
                                               bf16* __restrict__ rhi,
                                               bf16* __restrict__ rlo) {
    int row  = blockIdx.x * 4 + (threadIdx.x >> 6);
    int lane = threadIdx.x & 63;
    const float* src = (row < BHALF) ? (zis + (size_t)row * DDIM)
                                     : (zjs + (size_t)(row - BHALF) * DDIM);
    float2 v = ((const float2*)src)[lane];
    float ss = v.x * v.x + v.y * v.y;
    #pragma unroll
    for (int off = 1; off < 64; off <<= 1) ss += __shfl_xor(ss, off);
    float invs = SCF / fmaxf(sqrtf(ss), 1e-12f);
    float y0 = v.x * invs, y1 = v.y * invs;
    bf16 h0 = (bf16)y0, h1 = (bf16)y1;
    bf16 l0 = (bf16)(y0 - (float)h0), l1 = (bf16)(y1 - (float)h1);
    bf16x2 hv, lv;
    hv[0] = h0; hv[1] = h1; lv[0] = l0; lv[1] = l1;
    *(bf16x2*)(rhi + (size_t)row * DDIM + 2 * lane) = hv;
    *(bf16x2*)(rlo + (size_t)row * DDIM + 2 * lane) = lv;
}

// ---------------------------------------------------------------------------
// Kernel 2: sim GEMM (3-pass split-bf16 MFMA) + fused exp2 sum.
// 512 threads = 8 waves; each wave owns 16 rows -> row frags = 32 VGPRs, so
// everything stays register-resident at the compiler's 64-VGPR/8-wave budget
// (R7 post-mortem: 32-rows/wave forced fragment rematerialization).
// LDS 32KB double-buffered; 4 blocks/CU = 32 waves/CU.
// ---------------------------------------------------------------------------
__global__ __launch_bounds__(512, 4) void nt_sim(const bf16* __restrict__ rhi,
                                                 const bf16* __restrict__ rlo,
                                                 float* __restrict__ partial,
                                                 float* __restrict__ posA) {
    // LDS: 2 buffers x (hi 8KB + lo 8KB) = 32 KB
    __shared__ __align__(16) char smem[32768];

    const int tid  = threadIdx.x;
    const int lane = tid & 63;
    const int w    = tid >> 6;      // wave 0..7
    const int q    = lane >> 4;     // 0..3
    const int r15  = lane & 15;

    const int i0 = blockIdx.x * 128;              // block row base
    const int j0 = blockIdx.y * COLS_PER_BLOCK;   // block col base
    const bool capture = (blockIdx.y == (unsigned)((i0 ^ BHALF) >> 9));

    // ---- row fragments (B operand), VGPR-resident: 8 frags = 32 VGPRs ----
    const int myrow = i0 + w * 16 + r15;
    bf16x8 rh[4], rl[4];
    #pragma unroll
    for (int kk = 0; kk < 4; ++kk) {
        rh[kk] = *(const bf16x8*)(rhi + (size_t)myrow * DDIM + kk * 32 + q * 8);
        rl[kk] = *(const bf16x8*)(rlo + (size_t)myrow * DDIM + kk * 32 + q * 8);
    }

    float s[4] = {0.0f, 0.0f, 0.0f, 0.0f};

    // staging map: thread covers (col = w*4 + lane>>4, slot = lane&15);
    // dst = region + w*1024 + lane*16 (wave-uniform base + lane*16);
    // source slot inverse-swizzled: (slot ^ (col&7)).
    const int scol  = w * 4 + (lane >> 4);
    const int sslot = (r15 ^ (scol & 7)) << 3;    // bf16 offset (x8 = x16B)

    for (int c = 0; c <= NCHUNK; ++c) {
        // ---- stage chunk c into buffer c&1 ----
        if (c < NCHUNK) {
            char* dstb = smem + (c & 1) * 16384 + w * 1024 + (r15 << 4)
                       + ((lane >> 4) << 8);
            const size_t srow = (size_t)(j0 + c * CHUNK + scol) * DDIM + sslot;
            __builtin_amdgcn_global_load_lds(
                (const __attribute__((address_space(1))) void*)(rhi + srow),
                (__attribute__((address_space(3))) void*)dstb, 16, 0, 0);
            __builtin_amdgcn_global_load_lds(
                (const __attribute__((address_space(1))) void*)(rlo + srow),
                (__attribute__((address_space(3))) void*)(dstb + 8192), 16, 0, 0);
        }
        if (c == 0) { __syncthreads(); continue; }

        // ---- compute chunk c-1 from buffer (c-1)&1 ----
        const char* bh = smem + ((c - 1) & 1) * 16384;
        const char* bl = bh + 8192;
        const int cc = c - 1;
        #pragma unroll
        for (int jt = 0; jt < 2; ++jt) {
            const int cb = jt * 4096 + r15 * 256;
            f32x4 a = {-C2F, -C2F, -C2F, -C2F};
            #pragma unroll
            for (int kk = 0; kk < 4; ++kk) {
                const int pok = ((((kk << 2) | q)) ^ (r15 & 7)) << 4;
                bf16x8 ch = *(const bf16x8*)(bh + cb + pok);
                bf16x8 cl = *(const bf16x8*)(bl + cb + pok);
                MFMA(a, ch, rh[kk]);
                MFMA(a, ch, rl[kk]);
                MFMA(a, cl, rh[kk]);
            }
            // epilogue: 4 exp2 + 4 adds per jt-tile (no mask, no fma)
            #pragma unroll
            for (int r = 0; r < 4; ++r) s[r] += exp2f(a[r]);
            // positive-pair logit capture (wave-uniform skip in 15/16 blocks)
            if (capture) {
                const int jbase = j0 + cc * CHUNK + jt * 16;
                const int rel = (myrow ^ BHALF) - jbase;
                float v01 = (rel & 1) ? a[1] : a[0];
                float v23 = (rel & 1) ? a[3] : a[2];
                float v   = (rel & 2) ? v23 : v01;
                if (rel >= 0 && rel < 16 && (rel >> 2) == q) posA[myrow] = v;
            }
        }
        __syncthreads();
    }

    // ---- per-row totals: reduce regs, then over q groups ----
    float st = (s[0] + s[1]) + (s[2] + s[3]);
    st += __shfl_xor(st, 16);
    st += __shfl_xor(st, 32);
    if (q == 0) partial[(size_t)blockIdx.y * NROWS + myrow] = st;
}

// ---------------------------------------------------------------------------
// Kernel 3: merge partials, lse = 2 + log(sum - 1), pos = 2*(a+C2)/C2,
// mean over rows. 8 blocks + one atomicAdd each (out pre-zeroed by memset).
// ---------------------------------------------------------------------------
__global__ __launch_bounds__(1024) void nt_final(const float* __restrict__ partial,
                                                 const float* __restrict__ posA,
                                                 float* __restrict__ out) {
    int i = blockIdx.x * 1024 + threadIdx.x;
    float ssum = 0.0f;
    #pragma unroll
    for (int p = 0; p < NSPLIT; ++p) ssum += partial[(size_t)p * NROWS + i];
    float a = posA[i];                        // C2*dot_pos - C2
    float acc = 2.0f + logf(ssum - 1.0f) - 2.0f * (a + C2F) / C2F;

    #pragma unroll
    for (int off = 1; off < 64; off <<= 1) acc += __shfl_xor(acc, off);
    __shared__ float wsum[16];
    int tid = threadIdx.x;
    if ((tid & 63) == 0) wsum[tid >> 6] = acc;
    __syncthreads();
    if (tid == 0) {
        float t = 0.0f;
        #pragma unroll
        for (int k = 0; k < 16; ++k) t += wsum[k];
        atomicAdd(out, t * (1.0f / (float)NROWS));
    }
}

// ---------------------------------------------------------------------------
extern "C" void kernel_launch(void* const* d_in, const int* in_sizes, int n_in,
                              void* d_out, int out_size, void* d_ws, size_t ws_size,
                              hipStream_t stream) {
    const float* zis = (const float*)d_in[0];
    const float* zjs = (const float*)d_in[1];
    float* out = (float*)d_out;

    char* ws = (char*)d_ws;
    bf16*  rhi     = (bf16*)ws;                                   // 2 MB
    bf16*  rlo     = (bf16*)(ws + (size_t)NROWS * DDIM * 2);      // 2 MB
    float* partial = (float*)(ws + (size_t)NROWS * DDIM * 4);     // 512 KB
    float* posA    = (float*)(ws + (size_t)NROWS * DDIM * 4
                                 + (size_t)NSPLIT * NROWS * 4);   // 32 KB

    hipMemsetAsync(out, 0, sizeof(float), stream);
    nt_prep <<<NROWS / 4, 256, 0, stream>>>(zis, zjs, rhi, rlo);
    nt_sim  <<<dim3(NROWS / 128, NSPLIT), 512, 0, stream>>>(rhi, rlo, partial, posA);
    nt_final<<<NROWS / 1024, 1024, 0, stream>>>(partial, posA, out);
}